// Round 1
// baseline (113.021 us; speedup 1.0000x reference)
//
#include <hip/hip_runtime.h>
#include <math.h>

#define F_    16
#define NV_   4096
#define NT_   512
#define M_    4096
#define PPF_  (NV_ + NT_)        // 4608 points per frame
#define NPTS_ (F_ * PPF_)        // 73728 total points
#define SCALE_INV 10.0f          // 1 / 0.1

#define TPB     256
#define PTSB    64               // points per block; 4608/64=72 -> block never straddles a frame
#define NBLK    (NPTS_ / PTSB)   // 1152 blocks = 4.5/CU
#define CHUNK   128              // model points staged per iteration
#define NCHUNK  (M_ / CHUNK)     // 32
#define NSPLIT  32               // model-splits of each chunk (one per 8-thread group)
#define MPS     (CHUNK / NSPLIT) // 4 models per split per chunk
#define PPT     8                // points per thread (amortizes LDS reads 1:28 vs VALU)

// ---------------------------------------------------------------- pose math
__device__ inline void rot_from_omega(float ox, float oy, float oz, float dt,
                                      float* R) {
    // R = I + sin(theta*dt)*S + (1-cos(theta*dt))*S^2,  S = skew(omega/max(theta,1e-8))
    float theta = sqrtf(ox * ox + oy * oy + oz * oz);
    float inv = 1.0f / fmaxf(theta, 1e-8f);
    float ax = ox * inv, ay = oy * inv, az = oz * inv;
    float s = sinf(theta * dt);
    float c = 1.0f - cosf(theta * dt);
    R[0] = 1.0f - c * (ay * ay + az * az);
    R[1] = -s * az + c * ax * ay;
    R[2] =  s * ay + c * ax * az;
    R[3] =  s * az + c * ax * ay;
    R[4] = 1.0f - c * (ax * ax + az * az);
    R[5] = -s * ax + c * ay * az;
    R[6] = -s * ay + c * ax * az;
    R[7] =  s * ax + c * ay * az;
    R[8] = 1.0f - c * (ax * ax + ay * ay);
}

__device__ inline void compute_pose_serial(int f, const float* state,
                                           const float* phys, const float* dts,
                                           float* t, float* R) {
    t[0] = state[0]; t[1] = state[1]; t[2] = state[2];
    rot_from_omega(state[3], state[4], state[5], 1.0f, R);
    for (int i = 1; i <= f; ++i) {
        float dt = dts[i];
        t[0] += phys[i * 12 + 6] * dt;
        t[1] += phys[i * 12 + 7] * dt;
        t[2] += phys[i * 12 + 8] * dt;
        float Rs[9];
        rot_from_omega(phys[i * 12 + 9], phys[i * 12 + 10], phys[i * 12 + 11], dt, Rs);
        float Rn[9];
        for (int r = 0; r < 3; ++r)
            for (int c2 = 0; c2 < 3; ++c2)
                Rn[r * 3 + c2] = Rs[r * 3 + 0] * R[0 + c2] +
                                 Rs[r * 3 + 1] * R[3 + c2] +
                                 Rs[r * 3 + 2] * R[6 + c2];
        for (int j = 0; j < 9; ++j) R[j] = Rn[j];
    }
}

// ---------------------------------------------------------------- one kernel, zero workspace
// Block = 64 points x full 4096-model min. Threads: point-group pg = t&7 (8 points
// each), model-split sp = t>>3 (4 models of each 128-chunk). rot = t&3 rotates each
// lane's visiting order within its split so inner-loop LDS reads are per-lane
// strided (guaranteed conflict-free) instead of wave-uniform broadcast b128.
__global__ __launch_bounds__(TPB) void chamfer_one(
    const float* __restrict__ state, const float* __restrict__ model,
    const float* __restrict__ vis, const float* __restrict__ tac,
    const float* __restrict__ phys, const float* __restrict__ dts,
    float* __restrict__ out) {
    __shared__ float4 featD[2][TPB];        // [dbuf][sp*8 + entry]; entry e -> model 4*sp + (e&3) (duplicated)
    __shared__ float  sposes[F_ * 12];
    __shared__ float  sdm[PTSB][NSPLIT + 1]; // +1 pad: conflict-free column reads

    const int t = threadIdx.x;

    // poses (threads 0..15; identical arithmetic to the reference chain)
    if (t < F_) {
        float tr[3], R[9];
        compute_pose_serial(t, state, phys, dts, tr, R);
        float* o = sposes + t * 12;
        o[0] = tr[0]; o[1] = tr[1]; o[2] = tr[2];
        for (int j = 0; j < 9; ++j) o[3 + j] = R[j] * SCALE_INV;  // fold 1/SCALE
    }

    // stage chunk 0 (all 256 threads; each split's 4 features stored twice)
    {
        const int mi = (t >> 3) * MPS + (t & 3);
        float gx = model[mi * 3 + 0], gy = model[mi * 3 + 1], gz = model[mi * 3 + 2];
        featD[0][t] = make_float4(-2.0f * gx, -2.0f * gy, -2.0f * gz,
                                  gx * gx + gy * gy + gz * gz);
    }
    __syncthreads();

    const int pg  = t & 7;
    const int sp  = t >> 3;
    const int rot = t & 3;
    const int f   = (blockIdx.x * PTSB) / PPF_;   // uniform: block fits in one frame
    const int lbase = blockIdx.x * PTSB - f * PPF_;

    // transform my 8 points: c = (p - t) @ (R/SCALE)
    float c0[PPT], c1[PPT], c2[PPT], cn[PPT], dm[PPT];
#pragma unroll
    for (int k = 0; k < PPT; ++k) {
        int loc = lbase + pg * PPT + k;
        const float* p = (loc < NV_) ? (vis + ((size_t)f * NV_ + loc) * 3)
                                     : (tac + ((size_t)f * NT_ + (loc - NV_)) * 3);
        float px = p[0], py = p[1], pz = p[2];
        const float* ps = sposes + f * 12;
        float d0 = px - ps[0], d1 = py - ps[1], d2 = pz - ps[2];
        const float* R = ps + 3;
        float x = d0 * R[0] + d1 * R[3] + d2 * R[6];
        float y = d0 * R[1] + d1 * R[4] + d2 * R[7];
        float z = d0 * R[2] + d1 * R[5] + d2 * R[8];
        c0[k] = x; c1[k] = y; c2[k] = z;
        cn[k] = x * x + y * y + z * z;
        dm[k] = 3.4e38f;
    }

    // chunks: double-buffered staging, one barrier per chunk.
    for (int c = 0; c < NCHUNK; ++c) {
        const int cur = c & 1;
        if (c + 1 < NCHUNK) {   // prefetch next chunk into other buffer
            const int mi = (c + 1) * CHUNK + sp * MPS + (t & 3);
            float gx = model[mi * 3 + 0], gy = model[mi * 3 + 1], gz = model[mi * 3 + 2];
            featD[cur ^ 1][t] = make_float4(-2.0f * gx, -2.0f * gy, -2.0f * gz,
                                            gx * gx + gy * gy + gz * gz);
        }
        const float4* fb = &featD[cur][sp * 8];
#pragma unroll
        for (int m = 0; m < MPS; m += 2) {
            float4 ga = fb[rot + m];        // rotated order: min is order-invariant
            float4 gb = fb[rot + m + 1];    // entries rot..rot+3 cover all 4 models
#pragma unroll
            for (int k = 0; k < PPT; ++k) {
                float da = fmaf(ga.x, c0[k], fmaf(ga.y, c1[k], fmaf(ga.z, c2[k], ga.w)));
                float db = fmaf(gb.x, c0[k], fmaf(gb.y, c1[k], fmaf(gb.z, c2[k], gb.w)));
                dm[k] = fminf(dm[k], fminf(da, db));   // -> v_min3_f32
            }
        }
        __syncthreads();
    }

    // combine 32 split-partials per point, weight, block-sum, one atomicAdd
#pragma unroll
    for (int k = 0; k < PPT; ++k) sdm[pg * PPT + k][sp] = dm[k] + cn[k];
    __syncthreads();

    if (t < PTSB) {   // exactly wave 0
        float mn = sdm[t][0];
#pragma unroll
        for (int i = 1; i < NSPLIT; ++i) mn = fminf(mn, sdm[t][i]);
        const int loc = lbase + t;
        const float w = (loc < NV_) ? (1.0f / NV_) : (0.1f / NT_);
        float v = mn * w;
#pragma unroll
        for (int off = 32; off > 0; off >>= 1) v += __shfl_down(v, off);
        if (t == 0) atomicAdd(out, v);
    }
}

// ---------------------------------------------------------------- launch
// Deliberately touches NO workspace: theory is the harness re-poisons d_ws
// (256 MB fill, ~42 us, seen 2x in the dispatch stream) inside the timed
// region. d_ws is ignored entirely.
extern "C" void kernel_launch(void* const* d_in, const int* in_sizes, int n_in,
                              void* d_out, int out_size, void* d_ws, size_t ws_size,
                              hipStream_t stream) {
    const float* state = (const float*)d_in[0];   // (6,)
    const float* model = (const float*)d_in[1];   // (M,3)
    const float* vis   = (const float*)d_in[2];   // (F,NV,3)
    const float* tac   = (const float*)d_in[3];   // (F,NT,3)
    const float* phys  = (const float*)d_in[4];   // (F,12)
    const float* dts   = (const float*)d_in[5];   // (F,)
    float* out = (float*)d_out;
    (void)d_ws; (void)ws_size;

    hipMemsetAsync(out, 0, sizeof(float), stream);
    chamfer_one<<<NBLK, TPB, 0, stream>>>(state, model, vis, tac, phys, dts, out);
}

// Round 2
// 101.296 us; speedup vs baseline: 1.1158x; 1.1158x over previous
//
#include <hip/hip_runtime.h>
#include <math.h>

#define F_    16
#define NV_   4096
#define NT_   512
#define M_    4096
#define PPF_  (NV_ + NT_)        // 4608 points per frame
#define NPTS_ (F_ * PPF_)        // 73728 total points
#define SCALE_INV 10.0f          // 1 / 0.1

#define TPB   256
#define PTSB  96                 // points/block: 4608/96=48 -> no frame straddle; 73728/96=768 = 3 blocks/CU exactly
#define NBLK  (NPTS_ / PTSB)     // 768
#define NMG   8                  // model groups: one per HALF-WAVE -> <=2 distinct LDS addrs per read (free, m136)
#define MPG   (M_ / NMG)         // 512 models per group
#define CHM   64                 // models per group staged per chunk
#define NCH   (MPG / CHM)        // 8 chunks (8 barriers total)
#define FS    66                 // float4 stride per group: 66*16B -> +8-bank offset per group, halves fully disjoint
#define PPL   3                  // points per lane (32 point-lanes x 3 = 96)

// ---------------------------------------------------------------- pose math
__device__ inline void rot_from_omega(float ox, float oy, float oz, float dt,
                                      float* R) {
    // R = I + sin(theta*dt)*S + (1-cos(theta*dt))*S^2,  S = skew(omega/max(theta,1e-8))
    float theta = sqrtf(ox * ox + oy * oy + oz * oz);
    float inv = 1.0f / fmaxf(theta, 1e-8f);
    float ax = ox * inv, ay = oy * inv, az = oz * inv;
    float s = sinf(theta * dt);
    float c = 1.0f - cosf(theta * dt);
    R[0] = 1.0f - c * (ay * ay + az * az);
    R[1] = -s * az + c * ax * ay;
    R[2] =  s * ay + c * ax * az;
    R[3] =  s * az + c * ax * ay;
    R[4] = 1.0f - c * (ax * ax + az * az);
    R[5] = -s * ax + c * ay * az;
    R[6] = -s * ay + c * ax * az;
    R[7] =  s * ax + c * ay * az;
    R[8] = 1.0f - c * (ax * ax + ay * ay);
}

// ---------------------------------------------------------------- fused kernel
// Block = 96 points x all 4096 models, zero workspace (ws poison fill is
// unconditional -- round-1 evidence -- so ws buys nothing; fewer launches win).
// Thread layout: pl = t&31 (point lane), mg = t>>5 (model group, 2 per wave).
// Inner-loop ds_read_b128 is uniform per half-wave: 2 distinct addresses per
// wave, padded to disjoint bank groups via FS=66 -> zero bank conflicts.
__global__ __launch_bounds__(TPB) void chamfer_one(
    const float* __restrict__ state, const float* __restrict__ model,
    const float* __restrict__ vis, const float* __restrict__ tac,
    const float* __restrict__ phys, const float* __restrict__ dts,
    float* __restrict__ out) {
    __shared__ float4 featD[2][NMG * FS];   // double-buffered model features {-2g, |g|^2}
    __shared__ float  sposes[F_ * 12];
    __shared__ float  sRs[F_ * 9];
    __shared__ float  sdt[F_ * 3];
    __shared__ float  sdm[PTSB][NMG + 1];   // +1 pad: odd stride -> conflict-free
    __shared__ float  sw[2];

    const int t = threadIdx.x;

    // ---- poses (wave 0 only, lockstep -- no barrier needed inside) ----
    // Threads 0..15 compute their step rotation in parallel (one sin/cos each);
    // thread 0 then composes the chain serially with the exact reference
    // association (Rn = Rs @ R), so numerics match the jax scan.
    if (t < F_) {
        float ox, oy, oz, dt;
        if (t == 0) { ox = state[3]; oy = state[4]; oz = state[5]; dt = 1.0f; }
        else        { ox = phys[t * 12 + 9]; oy = phys[t * 12 + 10];
                      oz = phys[t * 12 + 11]; dt = dts[t]; }
        float Rs[9];
        rot_from_omega(ox, oy, oz, dt, Rs);
        for (int j = 0; j < 9; ++j) sRs[t * 9 + j] = Rs[j];
        if (t > 0) {
            sdt[t * 3 + 0] = phys[t * 12 + 6] * dt;
            sdt[t * 3 + 1] = phys[t * 12 + 7] * dt;
            sdt[t * 3 + 2] = phys[t * 12 + 8] * dt;
        }
    }
    if (t == 0) {
        float R[9];
        for (int j = 0; j < 9; ++j) R[j] = sRs[j];
        float tr[3] = {state[0], state[1], state[2]};
        for (int i = 0; i < F_; ++i) {
            if (i > 0) {
                tr[0] += sdt[i * 3 + 0];
                tr[1] += sdt[i * 3 + 1];
                tr[2] += sdt[i * 3 + 2];
                float Rn[9];
                const float* Rsp = sRs + i * 9;
                for (int r = 0; r < 3; ++r)
                    for (int c2 = 0; c2 < 3; ++c2)
                        Rn[r * 3 + c2] = Rsp[r * 3 + 0] * R[0 + c2] +
                                         Rsp[r * 3 + 1] * R[3 + c2] +
                                         Rsp[r * 3 + 2] * R[6 + c2];
                for (int j = 0; j < 9; ++j) R[j] = Rn[j];
            }
            float* o = sposes + i * 12;
            o[0] = tr[0]; o[1] = tr[1]; o[2] = tr[2];
            for (int j = 0; j < 9; ++j) o[3 + j] = R[j] * SCALE_INV;  // fold 1/SCALE
        }
    }

    // ---- stage chunk 0 (all 256 threads: 2 models each) ----
    {
        const int g = t >> 5, m = t & 31;
        int id = g * MPG + m;                       // chunk 0
        float gx = model[id * 3 + 0], gy = model[id * 3 + 1], gz = model[id * 3 + 2];
        featD[0][g * FS + m] = make_float4(-2.0f * gx, -2.0f * gy, -2.0f * gz,
                                           gx * gx + gy * gy + gz * gz);
        id += 32;
        gx = model[id * 3 + 0]; gy = model[id * 3 + 1]; gz = model[id * 3 + 2];
        featD[0][g * FS + m + 32] = make_float4(-2.0f * gx, -2.0f * gy, -2.0f * gz,
                                                gx * gx + gy * gy + gz * gz);
    }
    __syncthreads();

    const int pl = t & 31;
    const int mg = t >> 5;
    const int f = (blockIdx.x * PTSB) / PPF_;       // uniform: no frame straddle
    const int lbase = blockIdx.x * PTSB - f * PPF_;

    // ---- transform my 3 points: c = (p - t) @ (R/SCALE) ----
    float c0[PPL], c1[PPL], c2[PPL], cn[PPL], dm[PPL];
    {
        const float* ps = sposes + f * 12;
#pragma unroll
        for (int k = 0; k < PPL; ++k) {
            int loc = lbase + k * 32 + pl;
            const float* p = (loc < NV_) ? (vis + ((size_t)f * NV_ + loc) * 3)
                                         : (tac + ((size_t)f * NT_ + (loc - NV_)) * 3);
            float px = p[0], py = p[1], pz = p[2];
            float d0 = px - ps[0], d1 = py - ps[1], d2 = pz - ps[2];
            const float* R = ps + 3;
            float x = d0 * R[0] + d1 * R[3] + d2 * R[6];
            float y = d0 * R[1] + d1 * R[4] + d2 * R[7];
            float z = d0 * R[2] + d1 * R[5] + d2 * R[8];
            c0[k] = x; c1[k] = y; c2[k] = z;
            cn[k] = x * x + y * y + z * z;
            dm[k] = 3.4e38f;
        }
    }

    // ---- main loop: 8 chunks x 64 models (per group), double-buffered ----
    for (int c = 0; c < NCH; ++c) {
        const int cur = c & 1;
        if (c + 1 < NCH) {   // prefetch next chunk into other buffer
            const int g = t >> 5, m = t & 31;
            int id = g * MPG + (c + 1) * CHM + m;
            float gx = model[id * 3 + 0], gy = model[id * 3 + 1], gz = model[id * 3 + 2];
            featD[cur ^ 1][g * FS + m] = make_float4(-2.0f * gx, -2.0f * gy, -2.0f * gz,
                                                     gx * gx + gy * gy + gz * gz);
            id += 32;
            gx = model[id * 3 + 0]; gy = model[id * 3 + 1]; gz = model[id * 3 + 2];
            featD[cur ^ 1][g * FS + m + 32] = make_float4(-2.0f * gx, -2.0f * gy, -2.0f * gz,
                                                          gx * gx + gy * gy + gz * gz);
        }
        const float4* fb = &featD[cur][mg * FS];    // uniform per half-wave
#pragma unroll
        for (int m = 0; m < CHM; m += 2) {
            float4 ga = fb[m];       // broadcast read: 2 distinct addrs/wave, disjoint banks
            float4 gb = fb[m + 1];
#pragma unroll
            for (int k = 0; k < PPL; ++k) {
                float da = fmaf(ga.x, c0[k], fmaf(ga.y, c1[k], fmaf(ga.z, c2[k], ga.w)));
                float db = fmaf(gb.x, c0[k], fmaf(gb.y, c1[k], fmaf(gb.z, c2[k], gb.w)));
                dm[k] = fminf(dm[k], fminf(da, db));   // -> v_min3_f32
            }
        }
        __syncthreads();
    }

    // ---- combine 8 group-partials per point, weight, block-sum, one atomic ----
#pragma unroll
    for (int k = 0; k < PPL; ++k) sdm[k * 32 + pl][mg] = dm[k] + cn[k];
    __syncthreads();

    float v = 0.0f;
    if (t < PTSB) {
        float mn = sdm[t][0];
#pragma unroll
        for (int i = 1; i < NMG; ++i) mn = fminf(mn, sdm[t][i]);
        const int loc = lbase + t;
        const float w = (loc < NV_) ? (1.0f / NV_) : (0.1f / NT_);
        v = mn * w;
    }
    if (t < 128) {
#pragma unroll
        for (int off = 32; off > 0; off >>= 1) v += __shfl_down(v, off);
        if ((t & 63) == 0) sw[t >> 6] = v;
    }
    __syncthreads();
    if (t == 0) atomicAdd(out, sw[0] + sw[1]);
}

// ---------------------------------------------------------------- launch
// d_ws deliberately unused: round-1 showed the 256MB ws poison fill (~42us)
// runs unconditionally, so touching ws buys nothing and extra kernels cost
// launch gaps. Single fused kernel + 4-byte memset.
extern "C" void kernel_launch(void* const* d_in, const int* in_sizes, int n_in,
                              void* d_out, int out_size, void* d_ws, size_t ws_size,
                              hipStream_t stream) {
    const float* state = (const float*)d_in[0];   // (6,)
    const float* model = (const float*)d_in[1];   // (M,3)
    const float* vis   = (const float*)d_in[2];   // (F,NV,3)
    const float* tac   = (const float*)d_in[3];   // (F,NT,3)
    const float* phys  = (const float*)d_in[4];   // (F,12)
    const float* dts   = (const float*)d_in[5];   // (F,)
    float* out = (float*)d_out;
    (void)d_ws; (void)ws_size;

    hipMemsetAsync(out, 0, sizeof(float), stream);
    chamfer_one<<<NBLK, TPB, 0, stream>>>(state, model, vis, tac, phys, dts, out);
}

// Round 3
// 94.556 us; speedup vs baseline: 1.1953x; 1.0713x over previous
//
#include <hip/hip_runtime.h>
#include <math.h>

#define F_    16
#define NV_   4096
#define NT_   512
#define M_    4096
#define PPF_  (NV_ + NT_)        // 4608 points per frame
#define NPTS_ (F_ * PPF_)        // 73728 total points
#define SCALE_INV 10.0f          // 1 / 0.1

#define TPB   256
#define PTSB  96                 // points/block: 48 blocks/frame (no straddle); 768 blocks = 3/CU exact
#define NBLK  (NPTS_ / PTSB)     // 768
#define NG    32                 // model groups (8 per wave: g = t>>3)
#define MPG   (M_ / NG)          // 128 models per group
#define CHM   32                 // models per group per chunk
#define NCH   (MPG / CHM)        // 4 chunks
#define FS    33                 // float4 stride/group: 33*16 mod 128 = 16 -> 8 groups/wave on 8 disjoint bank-quads
#define PPL   12                 // points per lane (8 point-lanes x 12 = 96)

// ---------------------------------------------------------------- pose math
__device__ inline void rot_from_omega(float ox, float oy, float oz, float dt,
                                      float* R) {
    // R = I + sin(theta*dt)*S + (1-cos(theta*dt))*S^2,  S = skew(omega/max(theta,1e-8))
    float theta = sqrtf(ox * ox + oy * oy + oz * oz);
    float inv = 1.0f / fmaxf(theta, 1e-8f);
    float ax = ox * inv, ay = oy * inv, az = oz * inv;
    float s = sinf(theta * dt);
    float c = 1.0f - cosf(theta * dt);
    R[0] = 1.0f - c * (ay * ay + az * az);
    R[1] = -s * az + c * ax * ay;
    R[2] =  s * ay + c * ax * az;
    R[3] =  s * az + c * ax * ay;
    R[4] = 1.0f - c * (ax * ax + az * az);
    R[5] = -s * ax + c * ay * az;
    R[6] = -s * ay + c * ax * az;
    R[7] =  s * ax + c * ay * az;
    R[8] = 1.0f - c * (ax * ax + ay * ay);
}

// ---------------------------------------------------------------- fused kernel
// Round-2 lesson: LDS pipe (per-CU, shared by 4 SIMDs) was 2.3x oversubscribed
// at 512 ds_read_b128/wave. This version: 12 points/lane per model read ->
// 42 VALU ops (84 cyc) per read vs <=48 cyc LDS demand -> VALU-bound.
// 8 distinct read addrs/wave land on the 8 disjoint bank quads (FS=33).
__global__ __launch_bounds__(TPB, 3) void chamfer_one(
    const float* __restrict__ state, const float* __restrict__ model,
    const float* __restrict__ vis, const float* __restrict__ tac,
    const float* __restrict__ phys, const float* __restrict__ dts,
    float* __restrict__ out) {
    __shared__ float4 featD[2][NG * FS];    // model features {-2g, |g|^2}, double-buffered
    __shared__ float4 spts[8][13];          // transformed points {c, |c|^2}; stride 13 -> disjoint quads
    __shared__ float  sposes[F_ * 12];
    __shared__ float  sRs[F_ * 9];
    __shared__ float  sdt[F_ * 3];
    __shared__ float  sdm[PTSB][NG + 1];    // per-point per-group partial mins (+1 pad, 33 odd)
    __shared__ float  sw[2];

    const int t  = threadIdx.x;
    const int g  = t >> 3;                  // model group 0..31 (8 lanes each)
    const int m0 = t & 7;
    const int pl = t & 7;                   // point-lane 0..7 (12 points each)
    const int f  = (blockIdx.x * PTSB) / PPF_;          // uniform per block
    const int lbase = blockIdx.x * PTSB - f * PPF_;

    // ---- poses (wave 0, lockstep): parallel step-rotations, serial compose ----
    if (t < F_) {
        float ox, oy, oz, dt;
        if (t == 0) { ox = state[3]; oy = state[4]; oz = state[5]; dt = 1.0f; }
        else        { ox = phys[t * 12 + 9]; oy = phys[t * 12 + 10];
                      oz = phys[t * 12 + 11]; dt = dts[t]; }
        float Rs[9];
        rot_from_omega(ox, oy, oz, dt, Rs);
        for (int j = 0; j < 9; ++j) sRs[t * 9 + j] = Rs[j];
        if (t > 0) {
            sdt[t * 3 + 0] = phys[t * 12 + 6] * dt;
            sdt[t * 3 + 1] = phys[t * 12 + 7] * dt;
            sdt[t * 3 + 2] = phys[t * 12 + 8] * dt;
        }
    }
    if (t == 0) {
        float R[9];
        for (int j = 0; j < 9; ++j) R[j] = sRs[j];
        float tr[3] = {state[0], state[1], state[2]};
        for (int i = 0; i < F_; ++i) {
            if (i > 0) {
                tr[0] += sdt[i * 3 + 0];
                tr[1] += sdt[i * 3 + 1];
                tr[2] += sdt[i * 3 + 2];
                float Rn[9];
                const float* Rsp = sRs + i * 9;
                for (int r = 0; r < 3; ++r)
                    for (int c2 = 0; c2 < 3; ++c2)
                        Rn[r * 3 + c2] = Rsp[r * 3 + 0] * R[0 + c2] +
                                         Rsp[r * 3 + 1] * R[3 + c2] +
                                         Rsp[r * 3 + 2] * R[6 + c2];
                for (int j = 0; j < 9; ++j) R[j] = Rn[j];
            }
            float* o = sposes + i * 12;
            o[0] = tr[0]; o[1] = tr[1]; o[2] = tr[2];
            for (int j = 0; j < 9; ++j) o[3 + j] = R[j] * SCALE_INV;  // fold 1/SCALE
        }
    }

    // ---- stage chunk 0: thread t -> group g, models m0+8j (4 each) ----
#pragma unroll
    for (int j2 = 0; j2 < 4; ++j2) {
        int id = g * MPG + m0 + 8 * j2;
        float gx = model[id * 3 + 0], gy = model[id * 3 + 1], gz = model[id * 3 + 2];
        featD[0][g * FS + m0 + 8 * j2] =
            make_float4(-2.0f * gx, -2.0f * gy, -2.0f * gz, gx * gx + gy * gy + gz * gz);
    }
    __syncthreads();

    // ---- transform the block's 96 points (threads 0..95, coalesced loads) ----
    if (t < PTSB) {
        int loc = lbase + t;
        const float* p = (loc < NV_) ? (vis + ((size_t)f * NV_ + loc) * 3)
                                     : (tac + ((size_t)f * NT_ + (loc - NV_)) * 3);
        float px = p[0], py = p[1], pz = p[2];
        const float* ps = sposes + f * 12;
        float d0 = px - ps[0], d1 = py - ps[1], d2 = pz - ps[2];
        const float* R = ps + 3;
        float x = d0 * R[0] + d1 * R[3] + d2 * R[6];
        float y = d0 * R[1] + d1 * R[4] + d2 * R[7];
        float z = d0 * R[2] + d1 * R[5] + d2 * R[8];
        spts[t / PPL][t % PPL] = make_float4(x, y, z, x * x + y * y + z * z);
    }
    __syncthreads();

    // ---- load my 12 points into registers (8 distinct addrs/wave, disjoint quads) ----
    float c0[PPL], c1[PPL], c2[PPL], cn[PPL], dm[PPL];
#pragma unroll
    for (int k = 0; k < PPL; ++k) {
        float4 p = spts[pl][k];
        c0[k] = p.x; c1[k] = p.y; c2[k] = p.z; cn[k] = p.w;
        dm[k] = 3.4e38f;
    }

    // ---- main loop: 4 chunks x 32 models/group, double-buffered ----
    for (int c = 0; c < NCH; ++c) {
        // issue next chunk's global loads FIRST (hide latency under compute)
        float mx[4], my[4], mz[4];
        if (c + 1 < NCH) {
#pragma unroll
            for (int j2 = 0; j2 < 4; ++j2) {
                int id = g * MPG + (c + 1) * CHM + m0 + 8 * j2;
                mx[j2] = model[id * 3 + 0];
                my[j2] = model[id * 3 + 1];
                mz[j2] = model[id * 3 + 2];
            }
        }
        const float4* fb = &featD[c & 1][g * FS];
#pragma unroll 8
        for (int m = 0; m < CHM; m += 2) {
            float4 ga = fb[m];
            float4 gb = fb[m + 1];
#pragma unroll
            for (int k = 0; k < PPL; ++k) {
                float da = fmaf(ga.x, c0[k], fmaf(ga.y, c1[k], fmaf(ga.z, c2[k], ga.w)));
                float db = fmaf(gb.x, c0[k], fmaf(gb.y, c1[k], fmaf(gb.z, c2[k], gb.w)));
                dm[k] = fminf(dm[k], fminf(da, db));   // -> v_min3_f32
            }
        }
        if (c + 1 < NCH) {
#pragma unroll
            for (int j2 = 0; j2 < 4; ++j2) {
                featD[(c + 1) & 1][g * FS + m0 + 8 * j2] =
                    make_float4(-2.0f * mx[j2], -2.0f * my[j2], -2.0f * mz[j2],
                                mx[j2] * mx[j2] + my[j2] * my[j2] + mz[j2] * mz[j2]);
            }
        }
        __syncthreads();
    }

    // ---- combine 32 group-partials per point, weight, block-sum, one atomic ----
#pragma unroll
    for (int k = 0; k < PPL; ++k) sdm[pl * PPL + k][g] = dm[k] + cn[k];
    __syncthreads();

    float v = 0.0f;
    if (t < PTSB) {
        const float* row = sdm[t];
        float mn = row[0];
#pragma unroll
        for (int i = 1; i < NG; ++i) mn = fminf(mn, row[i]);
        const int loc = lbase + t;
        const float w = (loc < NV_) ? (1.0f / NV_) : (0.1f / NT_);
        v = mn * w;
    }
    if (t < 128) {
#pragma unroll
        for (int off = 32; off > 0; off >>= 1) v += __shfl_down(v, off);
        if ((t & 63) == 0) sw[t >> 6] = v;
    }
    __syncthreads();
    if (t == 0) atomicAdd(out, sw[0] + sw[1]);
}

// ---------------------------------------------------------------- launch
// d_ws unused: the 256MB ws poison fill (~42us) runs unconditionally
// (round-1 evidence), so workspace buys nothing; single fused kernel.
extern "C" void kernel_launch(void* const* d_in, const int* in_sizes, int n_in,
                              void* d_out, int out_size, void* d_ws, size_t ws_size,
                              hipStream_t stream) {
    const float* state = (const float*)d_in[0];   // (6,)
    const float* model = (const float*)d_in[1];   // (M,3)
    const float* vis   = (const float*)d_in[2];   // (F,NV,3)
    const float* tac   = (const float*)d_in[3];   // (F,NT,3)
    const float* phys  = (const float*)d_in[4];   // (F,12)
    const float* dts   = (const float*)d_in[5];   // (F,)
    float* out = (float*)d_out;
    (void)d_ws; (void)ws_size;

    hipMemsetAsync(out, 0, sizeof(float), stream);
    chamfer_one<<<NBLK, TPB, 0, stream>>>(state, model, vis, tac, phys, dts, out);
}